// Round 17
// baseline (439.508 us; speedup 1.0000x reference)
//
#include <hip/hip_runtime.h>
#include <hip/hip_bf16.h>
#include <stdint.h>

#define ENC_B 8192
#define NFED  16384
#define INDIM 1024
#define LAT   512
#define SCALE (1.0f/512.0f)

typedef __attribute__((ext_vector_type(4))) float f32x4;
typedef __attribute__((ext_vector_type(8))) short short8;
typedef __attribute__((ext_vector_type(4))) short short4_t;

// f32 -> bf16, round-to-nearest-even (inputs are finite)
static __device__ __forceinline__ short f2bf(float x){
  union { float f; uint32_t u; } v; v.f = x;
  uint32_t r = v.u + 0x7FFFu + ((v.u >> 16) & 1u);
  return (short)(r >> 16);
}
static __device__ __forceinline__ float bf2f(short s){
  union { float f; uint32_t u; } v; v.u = ((uint32_t)(unsigned short)s) << 16; return v.f;
}

// async global->LDS, 16B per lane; LDS dest = wave-uniform base + lane*16
static __device__ __forceinline__ void gload16(const void* g, void* l){
  __builtin_amdgcn_global_load_lds(
      (const __attribute__((address_space(1))) void*)g,
      (__attribute__((address_space(3))) void*)l, 16, 0, 0);
}

// bijective XCD-chunk swizzle (nwg divisible by 8) — ONLY for kv_gemm (gridDim.x<8)
static __device__ __forceinline__ int xcd_swz(int lid, int nwg){
  return (lid & 7) * (nwg >> 3) + (lid >> 3);
}

// ---------------- kernel 1: domain_diff [1024][512] f32 -> ddT [512][1024] bf16 ----
__global__ void ddT_kernel(const float* __restrict__ dd, short* __restrict__ ddT){
  const int n = blockIdx.x;                 // 0..511
  for (int k = threadIdx.x; k < INDIM; k += 256)
    ddT[(size_t)n*INDIM + k] = f2bf(dd[(size_t)k*LAT + n]);
}

// ---------------- kernel 1b: enc [8192][512] f32 -> encb bf16 (scale folded) --------
__global__ __launch_bounds__(256) void encb_kernel(const float* __restrict__ enc,
                                                   short* __restrict__ encb){
  const int gid = blockIdx.x*256 + threadIdx.x;   // grid 2048 -> 4M elems, 8 each
  const size_t base = (size_t)gid * 8;
  float4 v0 = *(const float4*)(enc + base);
  float4 v1 = *(const float4*)(enc + base + 4);
  short8 s;
  s[0]=f2bf(v0.x*SCALE); s[1]=f2bf(v0.y*SCALE); s[2]=f2bf(v0.z*SCALE); s[3]=f2bf(v0.w*SCALE);
  s[4]=f2bf(v1.x*SCALE); s[5]=f2bf(v1.y*SCALE); s[6]=f2bf(v1.z*SCALE); s[7]=f2bf(v1.w*SCALE);
  *(short8*)(encb + base) = s;
}

// ---------------- kernel 1c: X [16384][1024] f32 -> Xb bf16 (no scale) --------------
__global__ __launch_bounds__(256) void xb_kernel(const float* __restrict__ X,
                                                 short* __restrict__ Xb){
  const int gid = blockIdx.x*256 + threadIdx.x;   // grid 8192 -> 16.8M elems, 8 each
  const size_t base = (size_t)gid * 8;
  float4 v0 = *(const float4*)(X + base);
  float4 v1 = *(const float4*)(X + base + 4);
  short8 s;
  s[0]=f2bf(v0.x); s[1]=f2bf(v0.y); s[2]=f2bf(v0.z); s[3]=f2bf(v0.w);
  s[4]=f2bf(v1.x); s[5]=f2bf(v1.y); s[6]=f2bf(v1.z); s[7]=f2bf(v1.w);
  *(short8*)(Xb + base) = s;
}

// ---------------- kernel 2: kv[16384][512] bf16 = Xb @ ddT^T (s-clone, K=1024) ------
__global__ __launch_bounds__(256, 4) void kv_gemm_kernel(const short* __restrict__ Xb,
                                                         const short* __restrict__ ddT,
                                                         short* __restrict__ kv){
  __shared__ __align__(16) char lds[32768 + 512]; // As 16K | Bs 16K ; epilogue Pt 32K
  short* As = (short*)lds;                        // [n 128][k 64] bf16 swizzled
  short* Bs = (short*)(lds + 16384);              // [m 128][k 64] bf16 swizzled
  const int t = threadIdx.x;
  const int lane = t & 63, w = t >> 6;
  const int lr = lane & 15, lg = lane >> 4;
  const int nwg = gridDim.x * gridDim.y;
  const int nid = xcd_swz(blockIdx.x + gridDim.x*blockIdx.y, nwg);
  const int bx = nid % gridDim.x, by = nid / gridDim.x;
  const int n0 = bx * 128;                        // dd columns
  const int m0 = by * 128;                        // X rows

  const short* asrc[4]; const short* bsrc[4];
  #pragma unroll
  for (int i=0;i<4;++i){
    int ca = i*256 + w*64 + lane;
    int row = ca >> 3;
    int kcs = (lane & 7) ^ (row & 7);
    asrc[i] = ddT + (size_t)(n0 + row)*INDIM + kcs*8;
    bsrc[i] = Xb  + (size_t)(m0 + row)*INDIM + kcs*8;
  }

  f32x4 acc[2][8];                                // [m-sub ri][n-sub dj]
  #pragma unroll
  for (int i=0;i<2;++i)
    #pragma unroll
    for (int j=0;j<8;++j) acc[i][j] = (f32x4){0.f,0.f,0.f,0.f};

  for (int ks = 0; ks < 16; ++ks){                // K = 16 x 64
    #pragma unroll
    for (int i=0;i<4;++i){
      gload16(asrc[i], (char*)As + i*4096 + w*1024);
      gload16(bsrc[i], (char*)Bs + i*4096 + w*1024);
      asrc[i] += 64; bsrc[i] += 64;
    }
    __syncthreads();                              // drains vmcnt: tiles ready

    #pragma unroll
    for (int kk=0;kk<2;++kk){
      const uint32_t kbyte = (uint32_t)(kk*64 + lg*16);
      short8 b[2];
      #pragma unroll
      for (int ri=0;ri<2;++ri){
        int row = w*32 + ri*16 + lr;
        b[ri] = *(short8*)((char*)Bs + row*128 + (kbyte ^ ((uint32_t)(row & 7) << 4)));
      }
      #pragma unroll
      for (int h=0;h<2;++h){
        short8 a[4];
        #pragma unroll
        for (int j=0;j<4;++j){
          int row = (h*4 + j)*16 + lr;
          a[j] = *(short8*)((char*)As + row*128 + (kbyte ^ ((uint32_t)(row & 7) << 4)));
        }
        #pragma unroll
        for (int ri=0;ri<2;++ri)
          #pragma unroll
          for (int j=0;j<4;++j)
            acc[ri][h*4+j] = __builtin_amdgcn_mfma_f32_16x16x32_bf16(a[j], b[ri], acc[ri][h*4+j], 0,0,0);
      }
    }
    __syncthreads();                              // LDS consumed; safe to restage
  }

  // ---- epilogue: bf16 -> Pt (swizzled LDS) -> coalesced 16B stores ----
  char* Pt = lds;                                 // 32 KB, [m 128][n 128] bf16
  #pragma unroll
  for (int ri=0;ri<2;++ri){
    const int m = w*32 + ri*16 + lr;              // local m row 0..127
    const uint32_t rswz = ((uint32_t)(m & 7)) << 4;
    #pragma unroll
    for (int dj=0;dj<8;++dj){
      short4_t pv;
      #pragma unroll
      for (int r=0;r<4;++r) pv[r] = f2bf(acc[ri][dj][r]);
      *(short4_t*)(Pt + m*256 + (((uint32_t)(dj*32 + lg*8)) ^ rswz)) = pv;
    }
  }
  __syncthreads();
  #pragma unroll
  for (int i=0;i<8;++i){                          // 2048 chunks of 16B = full tile
    uint32_t c = (uint32_t)(i*256 + t);
    uint32_t row = c >> 4, c16 = c & 15;
    short8 v = *(short8*)(Pt + row*256 + ((c16*16) ^ (((uint32_t)(row & 7)) << 4)));
    *(short8*)(kv + (size_t)(m0 + row)*LAT + n0 + c16*8) = v;
  }
}

// ---------------- kernel 2b: kvT[512][16384] = transpose(kv) ------------------------
__global__ __launch_bounds__(256) void kvT_kernel(const short* __restrict__ kv,
                                                  short* __restrict__ kvT){
  __shared__ short tile[64][72];
  const int t = threadIdx.x;
  const int bn = blockIdx.x & (NFED/64 - 1);
  const int bd = blockIdx.x / (NFED/64);
  #pragma unroll
  for (int i=0;i<2;++i){
    int idx = t + i*256; int row = idx >> 3, cc = (idx & 7)*8;
    *(uint4*)&tile[row][cc] = *(const uint4*)(kv + (size_t)(bn*64+row)*LAT + bd*64 + cc);
  }
  __syncthreads();
  #pragma unroll
  for (int i=0;i<2;++i){
    int idx = t + i*256; int drow = idx >> 3, nn = (idx & 7)*8;
    short8 v;
    #pragma unroll
    for (int j=0;j<8;++j) v[j] = tile[nn+j][drow];
    *(short8*)(kvT + (size_t)(bd*64+drow)*NFED + bn*64 + nn) = v;
  }
}

// ---------------- kernel 5: S GEMM (z-clone) + exp + LDS-repack coalesced stores ----
// Natural blockIdx mapping (bx fastest): each XCD keeps a fixed kv-panel subset.
__global__ __launch_bounds__(256, 4) void s_gemm_kernel(const short* __restrict__ encb,
                                                        const short* __restrict__ kv,
                                                        short* __restrict__ Pc,
                                                        float* __restrict__ lpart,
                                                        int cbase, int chunk){
  __shared__ __align__(16) char lds[32768 + 512]; // As 16K | Bs 16K ; epilogue: Pt 32K | lsum
  short* As = (short*)lds;
  short* Bs = (short*)(lds + 16384);
  const int t = threadIdx.x;
  const int lane = t & 63, w = t >> 6;
  const int lr = lane & 15, lg = lane >> 4;
  const int n0g = cbase + blockIdx.x * 128;      // global key base
  const int m0  = blockIdx.y * 128;              // q-row base

  const short* asrc[4]; const short* bsrc[4];
  #pragma unroll
  for (int i=0;i<4;++i){
    int ca = i*256 + w*64 + lane;
    int row = ca >> 3;
    int kcs = (lane & 7) ^ (row & 7);
    asrc[i] = kv   + (size_t)(n0g + row)*LAT + kcs*8;
    bsrc[i] = encb + (size_t)(m0  + row)*LAT + kcs*8;
  }

  f32x4 acc[2][8];                               // [q-sub ri][key-sub dj]
  #pragma unroll
  for (int i=0;i<2;++i)
    #pragma unroll
    for (int j=0;j<8;++j) acc[i][j] = (f32x4){0.f,0.f,0.f,0.f};

  for (int ks = 0; ks < 8; ++ks){                // d = 8 x 64
    #pragma unroll
    for (int i=0;i<4;++i){
      gload16(asrc[i], (char*)As + i*4096 + w*1024);
      gload16(bsrc[i], (char*)Bs + i*4096 + w*1024);
      asrc[i] += 64; bsrc[i] += 64;
    }
    __syncthreads();                             // drains vmcnt: tiles ready

    #pragma unroll
    for (int kk=0;kk<2;++kk){
      const uint32_t kbyte = (uint32_t)(kk*64 + lg*16);
      short8 b[2];
      #pragma unroll
      for (int ri=0;ri<2;++ri){
        int row = w*32 + ri*16 + lr;
        b[ri] = *(short8*)((char*)Bs + row*128 + (kbyte ^ ((uint32_t)(row & 7) << 4)));
      }
      #pragma unroll
      for (int h=0;h<2;++h){
        short8 a[4];
        #pragma unroll
        for (int j=0;j<4;++j){
          int row = (h*4 + j)*16 + lr;
          a[j] = *(short8*)((char*)As + row*128 + (kbyte ^ ((uint32_t)(row & 7) << 4)));
        }
        #pragma unroll
        for (int ri=0;ri<2;++ri)
          #pragma unroll
          for (int j=0;j<4;++j)
            acc[ri][h*4+j] = __builtin_amdgcn_mfma_f32_16x16x32_bf16(a[j], b[ri], acc[ri][h*4+j], 0,0,0);
      }
    }
    __syncthreads();                             // LDS consumed; safe to restage
  }

  // ---- epilogue: exp -> Pt (swizzled LDS), row sums; then coalesced 16B stores ----
  char*  Pt   = lds;                             // 32 KB, [q 128][key 128] bf16
  float* lsum = (float*)(lds + 32768);
  #pragma unroll
  for (int ri=0;ri<2;++ri){
    const int q = w*32 + ri*16 + lr;             // local q row 0..127
    const uint32_t rswz = ((uint32_t)(q & 7)) << 4;
    float ps = 0.f;
    #pragma unroll
    for (int dj=0;dj<8;++dj){
      short4_t pv;
      #pragma unroll
      for (int r=0;r<4;++r){
        float pe = __expf(acc[ri][dj][r]);
        ps += pe;
        pv[r] = f2bf(pe);
      }
      *(short4_t*)(Pt + q*256 + (((uint32_t)(dj*32 + lg*8)) ^ rswz)) = pv;
    }
    ps += __shfl_xor(ps, 16, 64);                // reduce over the 4 lg groups
    ps += __shfl_xor(ps, 32, 64);
    if (lg == 0) lsum[q] = ps;
  }
  __syncthreads();
  #pragma unroll
  for (int i=0;i<8;++i){                         // 2048 chunks of 16B = full 32KB tile
    uint32_t c = (uint32_t)(i*256 + t);
    uint32_t row = c >> 4, c16 = c & 15;
    short8 v = *(short8*)(Pt + row*256 + ((c16*16) ^ (((uint32_t)(row & 7)) << 4)));
    *(short8*)(Pc + (size_t)(m0 + row)*chunk + blockIdx.x*128 + c16*8) = v;
  }
  if (t < 128){
    int jsl = (cbase >> 7) + blockIdx.x;         // 128-key slice index
    lpart[(size_t)jsl*ENC_B + m0 + t] = lsum[t];
  }
}

// ---------------- kernel 6: Z GEMM, tile 128rows x 128d, BK=64, splitK=4 ------------
// zb[slice][512 d][8192 rows] bf16; slice = (c&1)*4 + s; pure write c<2, RMW c>=2.
// 32 MFMA per K-step per wave vs 8 staging loads (was 16:6). Pc re-read 4x (was 8x).
// grid dim3(ENC_B/128=64, LAT/128=4, 4 splitK), 256 thr, 4 blocks/CU.
__global__ __launch_bounds__(256, 4) void z_gemm_kernel(const short* __restrict__ kvT,
                                                        const short* __restrict__ Pc,
                                                        short* __restrict__ zb,
                                                        int cbase, int chunk,
                                                        int sliceBase, int first){
  __shared__ __align__(16) short As[128*64];     // 16 KB [d][k] swizzled
  __shared__ __align__(16) short Bs[128*64];     // 16 KB [row][k] swizzled
  const int t = threadIdx.x;
  const int lane = t & 63, w = t >> 6;
  const int lr = lane & 15, lg = lane >> 4;
  const int n0 = blockIdx.x * 128;               // q-rows
  const int m0 = blockIdx.y * 128;               // d
  const int s  = blockIdx.z;
  const int sl = sliceBase + s;
  const int klocal0 = s * (chunk >> 2);

  const short* asrc[4]; const short* bsrc[4];
  #pragma unroll
  for (int i=0;i<4;++i){
    int ca = i*256 + w*64 + lane;
    int row = ca >> 3;
    int kcs = (lane & 7) ^ (row & 7);
    asrc[i] = kvT + (size_t)(m0 + row)*NFED + cbase + klocal0 + kcs*8;
    bsrc[i] = Pc  + (size_t)(n0 + row)*chunk + klocal0 + kcs*8;
  }

  f32x4 acc[2][8];                               // [row-sub ri][d-sub dj]
  #pragma unroll
  for (int i=0;i<2;++i)
    #pragma unroll
    for (int j=0;j<8;++j) acc[i][j] = (f32x4){0.f,0.f,0.f,0.f};

  const int ksteps = chunk >> 8;                 // (chunk/4)/64
  for (int ks = 0; ks < ksteps; ++ks) {
    #pragma unroll
    for (int i=0;i<4;++i){
      gload16(asrc[i], (char*)As + i*4096 + w*1024);
      gload16(bsrc[i], (char*)Bs + i*4096 + w*1024);
      asrc[i] += 64; bsrc[i] += 64;
    }
    __syncthreads();                             // drains vmcnt: tiles ready

    #pragma unroll
    for (int kk=0;kk<2;++kk){
      const uint32_t kbyte = (uint32_t)(kk*64 + lg*16);
      short8 b[2];
      #pragma unroll
      for (int ri=0;ri<2;++ri){
        int row = w*32 + ri*16 + lr;
        b[ri] = *(short8*)((char*)Bs + row*128 + (kbyte ^ ((uint32_t)(row & 7) << 4)));
      }
      #pragma unroll
      for (int h=0;h<2;++h){
        short8 a[4];
        #pragma unroll
        for (int j=0;j<4;++j){
          int row = (h*4 + j)*16 + lr;
          a[j] = *(short8*)((char*)As + row*128 + (kbyte ^ ((uint32_t)(row & 7) << 4)));
        }
        #pragma unroll
        for (int ri=0;ri<2;++ri)
          #pragma unroll
          for (int j=0;j<4;++j)
            acc[ri][h*4+j] = __builtin_amdgcn_mfma_f32_16x16x32_bf16(a[j], b[ri], acc[ri][h*4+j], 0,0,0);
      }
    }
    __syncthreads();                             // LDS consumed; safe to restage
  }

  // epilogue: write (or RMW) bf16 slice, zb[sl][d][row]
  #pragma unroll
  for (int ri=0;ri<2;++ri)
    #pragma unroll
    for (int dj=0;dj<8;++dj)
      #pragma unroll
      for (int r=0;r<4;++r) {
        int d    = m0 + dj*16 + lg*4 + r;
        int rowq = n0 + w*32 + ri*16 + lr;
        size_t idx = ((size_t)sl*LAT + d)*ENC_B + rowq;
        float v = acc[ri][dj][r];
        if (!first) v += bf2f(zb[idx]);
        zb[idx] = f2bf(v);
      }
}

// ---------------- kernel 7: linv[row] = 1 / sum_j lpart[j][row] ---------------------
__global__ __launch_bounds__(256) void lred_kernel(const float* __restrict__ lpart,
                                                   float* __restrict__ linv){
  const int row = blockIdx.x*256 + threadIdx.x;  // grid 32
  float sum = 0.f;
  for (int j = 0; j < NFED/128; ++j)
    sum += lpart[(size_t)j*ENC_B + row];
  linv[row] = 1.0f / sum;
}

// ---------------- kernel 8: out[row][d] = (sum_sl zb[sl][d][row]) * linv[row] -------
__global__ __launch_bounds__(256) void zcomb_kernel(const short* __restrict__ zb,
                                                    const float* __restrict__ linv,
                                                    float* __restrict__ out){
  __shared__ float tile[64][65];
  const int t = threadIdx.x;
  const int bx = blockIdx.x;                     // row-tile 0..127
  const int by = blockIdx.y;                     // d-tile 0..7
  #pragma unroll
  for (int i=0;i<4;++i){
    int idx = t + i*256;                         // 1024 quads = 64x64
    int dr = idx >> 4, rc = (idx & 15)*4;
    float s0=0.f, s1=0.f, s2=0.f, s3=0.f;
    #pragma unroll
    for (int sl=0; sl<8; ++sl){
      short4_t v = *(const short4_t*)(zb + ((size_t)sl*LAT + by*64 + dr)*ENC_B + bx*64 + rc);
      s0 += bf2f(v[0]); s1 += bf2f(v[1]); s2 += bf2f(v[2]); s3 += bf2f(v[3]);
    }
    tile[dr][rc+0]=s0; tile[dr][rc+1]=s1; tile[dr][rc+2]=s2; tile[dr][rc+3]=s3;
  }
  __syncthreads();
  #pragma unroll
  for (int i=0;i<4;++i){
    int idx = t + i*256;
    int rr = idx >> 4, dc = (idx & 15)*4;
    float li = linv[bx*64 + rr];
    float4 o;
    o.x = tile[dc+0][rr]*li; o.y = tile[dc+1][rr]*li;
    o.z = tile[dc+2][rr]*li; o.w = tile[dc+3][rr]*li;
    *(float4*)(out + (size_t)(bx*64+rr)*LAT + by*64 + dc) = o;
  }
}

extern "C" void kernel_launch(void* const* d_in, const int* in_sizes, int n_in,
                              void* d_out, int out_size, void* d_ws, size_t ws_size,
                              hipStream_t stream) {
  const float* enc = (const float*)d_in[0];   // 8192 x 512
  const float* X   = (const float*)d_in[1];   // 16384 x 1024
  const float* dd  = (const float*)d_in[2];   // 1024 x 512
  float* out = (float*)d_out;                  // 8192 x 512 f32

  // ws layout (bytes):
  //   kv    @ 0          16,777,216
  //   kvT   @ 16,777,216 16,777,216
  //   encb  @ 33,554,432  8,388,608
  //   lpart @ 41,943,040  4,194,304   (ddT overlays, dead before lpart use)
  //   linv  @ 46,137,344     32,768
  //   zb    @ 50,331,648 67,108,864   (Xb overlays first 32MB, dead before z writes)
  //   Pc    @117,440,512 chunk*16384
  short* kvb   = (short*)d_ws;
  short* kvT   = (short*)((char*)d_ws + 16777216);
  short* encb  = (short*)((char*)d_ws + 33554432);
  float* lpart = (float*)((char*)d_ws + 41943040);
  short* ddT   = (short*)((char*)d_ws + 41943040);   // prep only
  float* linv  = (float*)((char*)d_ws + 46137344);
  short* zb    = (short*)((char*)d_ws + 50331648);
  short* Xb    = (short*)((char*)d_ws + 50331648);   // prep only (dead before z)
  short* Pc    = (short*)((char*)d_ws + 117440512);

  int chunk;
  if      (ws_size >= (size_t)117440512 + (size_t)4096*ENC_B*2) chunk = 4096;
  else if (ws_size >= (size_t)117440512 + (size_t)2048*ENC_B*2) chunk = 2048;
  else                                                          chunk = 1024;

  ddT_kernel<<<LAT, 256, 0, stream>>>(dd, ddT);
  xb_kernel<<<NFED*INDIM/(256*8), 256, 0, stream>>>(X, Xb);
  kv_gemm_kernel<<<dim3(LAT/128, NFED/128), 256, 0, stream>>>(Xb, ddT, kvb);
  kvT_kernel<<<(NFED/64)*(LAT/64), 256, 0, stream>>>(kvb, kvT);
  encb_kernel<<<ENC_B*LAT/(256*8), 256, 0, stream>>>(enc, encb);

  const int nc = NFED / chunk;
  for (int c = 0; c < nc; ++c) {
    s_gemm_kernel<<<dim3(chunk/128, ENC_B/128), 256, 0, stream>>>(
        encb, kvb, Pc, lpart, c*chunk, chunk);
    // slices: (c&1)*4 + splitK-quarter; pure write for c<2, bf16 RMW for c>=2
    z_gemm_kernel<<<dim3(ENC_B/128, LAT/128, 4), 256, 0, stream>>>(
        kvT, Pc, zb, c*chunk, chunk, (c & 1)*4, (c < 2) ? 1 : 0);
  }
  lred_kernel<<<ENC_B/256, 256, 0, stream>>>(lpart, linv);
  zcomb_kernel<<<dim3(ENC_B/64, LAT/64), 256, 0, stream>>>(zb, linv, out);
}

// Round 18
// 413.658 us; speedup vs baseline: 1.0625x; 1.0625x over previous
//
#include <hip/hip_runtime.h>
#include <hip/hip_bf16.h>
#include <stdint.h>

#define ENC_B 8192
#define NFED  16384
#define INDIM 1024
#define LAT   512
#define SCALE (1.0f/512.0f)

typedef __attribute__((ext_vector_type(4))) float f32x4;
typedef __attribute__((ext_vector_type(8))) short short8;
typedef __attribute__((ext_vector_type(4))) short short4_t;

// f32 -> bf16, round-to-nearest-even (inputs are finite)
static __device__ __forceinline__ short f2bf(float x){
  union { float f; uint32_t u; } v; v.f = x;
  uint32_t r = v.u + 0x7FFFu + ((v.u >> 16) & 1u);
  return (short)(r >> 16);
}
static __device__ __forceinline__ float bf2f(short s){
  union { float f; uint32_t u; } v; v.u = ((uint32_t)(unsigned short)s) << 16; return v.f;
}

// async global->LDS, 16B per lane; LDS dest = wave-uniform base + lane*16
static __device__ __forceinline__ void gload16(const void* g, void* l){
  __builtin_amdgcn_global_load_lds(
      (const __attribute__((address_space(1))) void*)g,
      (__attribute__((address_space(3))) void*)l, 16, 0, 0);
}

// bijective XCD-chunk swizzle (nwg divisible by 8) — ONLY for kv_gemm (gridDim.x<8)
static __device__ __forceinline__ int xcd_swz(int lid, int nwg){
  return (lid & 7) * (nwg >> 3) + (lid >> 3);
}

// ---------------- kernel 1: domain_diff [1024][512] f32 -> ddT [512][1024] bf16 ----
__global__ void ddT_kernel(const float* __restrict__ dd, short* __restrict__ ddT){
  const int n = blockIdx.x;                 // 0..511
  for (int k = threadIdx.x; k < INDIM; k += 256)
    ddT[(size_t)n*INDIM + k] = f2bf(dd[(size_t)k*LAT + n]);
}

// ---------------- kernel 1b: enc [8192][512] f32 -> encb bf16 (scale folded) --------
__global__ __launch_bounds__(256) void encb_kernel(const float* __restrict__ enc,
                                                   short* __restrict__ encb){
  const int gid = blockIdx.x*256 + threadIdx.x;   // grid 2048 -> 4M elems, 8 each
  const size_t base = (size_t)gid * 8;
  float4 v0 = *(const float4*)(enc + base);
  float4 v1 = *(const float4*)(enc + base + 4);
  short8 s;
  s[0]=f2bf(v0.x*SCALE); s[1]=f2bf(v0.y*SCALE); s[2]=f2bf(v0.z*SCALE); s[3]=f2bf(v0.w*SCALE);
  s[4]=f2bf(v1.x*SCALE); s[5]=f2bf(v1.y*SCALE); s[6]=f2bf(v1.z*SCALE); s[7]=f2bf(v1.w*SCALE);
  *(short8*)(encb + base) = s;
}

// ---------------- kernel 1c: X [16384][1024] f32 -> Xb bf16 (no scale) --------------
__global__ __launch_bounds__(256) void xb_kernel(const float* __restrict__ X,
                                                 short* __restrict__ Xb){
  const int gid = blockIdx.x*256 + threadIdx.x;   // grid 8192 -> 16.8M elems, 8 each
  const size_t base = (size_t)gid * 8;
  float4 v0 = *(const float4*)(X + base);
  float4 v1 = *(const float4*)(X + base + 4);
  short8 s;
  s[0]=f2bf(v0.x); s[1]=f2bf(v0.y); s[2]=f2bf(v0.z); s[3]=f2bf(v0.w);
  s[4]=f2bf(v1.x); s[5]=f2bf(v1.y); s[6]=f2bf(v1.z); s[7]=f2bf(v1.w);
  *(short8*)(Xb + base) = s;
}

// ---------------- kernel 2: kv + kvT fused GEMM ------------------------------------
// kv[16384][512] bf16 = Xb @ ddT^T ; kvT[512][16384] written from the same Pt tile.
// Pt swizzle: combined XOR ((q&7)^((q>>3)&7))<<4 so row-reads (kv), col-gathers (kvT)
// and P-writes all stay bank-spread. grid dim3(4,128), XCD-swizzled.
__global__ __launch_bounds__(256, 4) void kv_gemm_kernel(const short* __restrict__ Xb,
                                                         const short* __restrict__ ddT,
                                                         short* __restrict__ kv,
                                                         short* __restrict__ kvT){
  __shared__ __align__(16) char lds[32768 + 512]; // As 16K | Bs 16K ; epilogue Pt 32K
  short* As = (short*)lds;                        // [n 128][k 64] bf16 swizzled
  short* Bs = (short*)(lds + 16384);              // [m 128][k 64] bf16 swizzled
  const int t = threadIdx.x;
  const int lane = t & 63, w = t >> 6;
  const int lr = lane & 15, lg = lane >> 4;
  const int nwg = gridDim.x * gridDim.y;
  const int nid = xcd_swz(blockIdx.x + gridDim.x*blockIdx.y, nwg);
  const int bx = nid % gridDim.x, by = nid / gridDim.x;
  const int n0 = bx * 128;                        // dd columns (= kvT rows)
  const int m0 = by * 128;                        // X rows     (= kvT cols)

  const short* asrc[4]; const short* bsrc[4];
  #pragma unroll
  for (int i=0;i<4;++i){
    int ca = i*256 + w*64 + lane;
    int row = ca >> 3;
    int kcs = (lane & 7) ^ (row & 7);
    asrc[i] = ddT + (size_t)(n0 + row)*INDIM + kcs*8;
    bsrc[i] = Xb  + (size_t)(m0 + row)*INDIM + kcs*8;
  }

  f32x4 acc[2][8];                                // [m-sub ri][n-sub dj]
  #pragma unroll
  for (int i=0;i<2;++i)
    #pragma unroll
    for (int j=0;j<8;++j) acc[i][j] = (f32x4){0.f,0.f,0.f,0.f};

  for (int ks = 0; ks < 16; ++ks){                // K = 16 x 64
    #pragma unroll
    for (int i=0;i<4;++i){
      gload16(asrc[i], (char*)As + i*4096 + w*1024);
      gload16(bsrc[i], (char*)Bs + i*4096 + w*1024);
      asrc[i] += 64; bsrc[i] += 64;
    }
    __syncthreads();                              // drains vmcnt: tiles ready

    #pragma unroll
    for (int kk=0;kk<2;++kk){
      const uint32_t kbyte = (uint32_t)(kk*64 + lg*16);
      short8 b[2];
      #pragma unroll
      for (int ri=0;ri<2;++ri){
        int row = w*32 + ri*16 + lr;
        b[ri] = *(short8*)((char*)Bs + row*128 + (kbyte ^ ((uint32_t)(row & 7) << 4)));
      }
      #pragma unroll
      for (int h=0;h<2;++h){
        short8 a[4];
        #pragma unroll
        for (int j=0;j<4;++j){
          int row = (h*4 + j)*16 + lr;
          a[j] = *(short8*)((char*)As + row*128 + (kbyte ^ ((uint32_t)(row & 7) << 4)));
        }
        #pragma unroll
        for (int ri=0;ri<2;++ri)
          #pragma unroll
          for (int j=0;j<4;++j)
            acc[ri][h*4+j] = __builtin_amdgcn_mfma_f32_16x16x32_bf16(a[j], b[ri], acc[ri][h*4+j], 0,0,0);
      }
    }
    __syncthreads();                              // LDS consumed; safe to restage
  }

  // ---- epilogue: bf16 -> Pt (combined-XOR swizzle) -> kv rows + kvT columns ----
  char* Pt = lds;                                 // 32 KB, [m 128][n 128] bf16
  #pragma unroll
  for (int ri=0;ri<2;++ri){
    const int m = w*32 + ri*16 + lr;              // local m row 0..127
    const uint32_t rswz = ((uint32_t)((m & 7) ^ ((m >> 3) & 7))) << 4;
    #pragma unroll
    for (int dj=0;dj<8;++dj){
      short4_t pv;
      #pragma unroll
      for (int r=0;r<4;++r) pv[r] = f2bf(acc[ri][dj][r]);
      *(short4_t*)(Pt + m*256 + (((uint32_t)(dj*32 + lg*8)) ^ rswz)) = pv;
    }
  }
  __syncthreads();
  // kv stores: 2048 chunks of 16B, coalesced along n
  #pragma unroll
  for (int i=0;i<8;++i){
    uint32_t c = (uint32_t)(i*256 + t);
    uint32_t row = c >> 4, c16 = c & 15;
    uint32_t swz = ((uint32_t)((row & 7) ^ ((row >> 3) & 7))) << 4;
    short8 v = *(short8*)(Pt + row*256 + ((c16*16) ^ swz));
    *(short8*)(kv + (size_t)(m0 + row)*LAT + n0 + c16*8) = v;
  }
  // kvT stores: 2048 chunks (128 n x 16 m16); lanes cover consecutive m16 -> coalesced
  #pragma unroll
  for (int i=0;i<8;++i){
    uint32_t c = (uint32_t)(i*256 + t);
    uint32_t m16 = c & 15, n = c >> 4;            // n 0..127
    short8 v;
    #pragma unroll
    for (int j=0;j<8;++j){
      uint32_t m = m16*8 + j;
      uint32_t swz = ((uint32_t)((m & 7) ^ ((m >> 3) & 7))) << 4;
      v[j] = *(const short*)(Pt + m*256 + ((2u*n) ^ swz));
    }
    *(short8*)(kvT + (size_t)(n0 + n)*NFED + m0 + m16*8) = v;
  }
}

// ---------------- kernel 5: S GEMM (z-clone) + exp + LDS-repack coalesced stores ----
// Natural blockIdx mapping (bx fastest): each XCD keeps a fixed kv-panel subset.
__global__ __launch_bounds__(256, 4) void s_gemm_kernel(const short* __restrict__ encb,
                                                        const short* __restrict__ kv,
                                                        short* __restrict__ Pc,
                                                        float* __restrict__ lpart,
                                                        int cbase, int chunk){
  __shared__ __align__(16) char lds[32768 + 512]; // As 16K | Bs 16K ; epilogue: Pt 32K | lsum
  short* As = (short*)lds;
  short* Bs = (short*)(lds + 16384);
  const int t = threadIdx.x;
  const int lane = t & 63, w = t >> 6;
  const int lr = lane & 15, lg = lane >> 4;
  const int n0g = cbase + blockIdx.x * 128;      // global key base
  const int m0  = blockIdx.y * 128;              // q-row base

  const short* asrc[4]; const short* bsrc[4];
  #pragma unroll
  for (int i=0;i<4;++i){
    int ca = i*256 + w*64 + lane;
    int row = ca >> 3;
    int kcs = (lane & 7) ^ (row & 7);
    asrc[i] = kv   + (size_t)(n0g + row)*LAT + kcs*8;
    bsrc[i] = encb + (size_t)(m0  + row)*LAT + kcs*8;
  }

  f32x4 acc[2][8];                               // [q-sub ri][key-sub dj]
  #pragma unroll
  for (int i=0;i<2;++i)
    #pragma unroll
    for (int j=0;j<8;++j) acc[i][j] = (f32x4){0.f,0.f,0.f,0.f};

  for (int ks = 0; ks < 8; ++ks){                // d = 8 x 64
    #pragma unroll
    for (int i=0;i<4;++i){
      gload16(asrc[i], (char*)As + i*4096 + w*1024);
      gload16(bsrc[i], (char*)Bs + i*4096 + w*1024);
      asrc[i] += 64; bsrc[i] += 64;
    }
    __syncthreads();                             // drains vmcnt: tiles ready

    #pragma unroll
    for (int kk=0;kk<2;++kk){
      const uint32_t kbyte = (uint32_t)(kk*64 + lg*16);
      short8 b[2];
      #pragma unroll
      for (int ri=0;ri<2;++ri){
        int row = w*32 + ri*16 + lr;
        b[ri] = *(short8*)((char*)Bs + row*128 + (kbyte ^ ((uint32_t)(row & 7) << 4)));
      }
      #pragma unroll
      for (int h=0;h<2;++h){
        short8 a[4];
        #pragma unroll
        for (int j=0;j<4;++j){
          int row = (h*4 + j)*16 + lr;
          a[j] = *(short8*)((char*)As + row*128 + (kbyte ^ ((uint32_t)(row & 7) << 4)));
        }
        #pragma unroll
        for (int ri=0;ri<2;++ri)
          #pragma unroll
          for (int j=0;j<4;++j)
            acc[ri][h*4+j] = __builtin_amdgcn_mfma_f32_16x16x32_bf16(a[j], b[ri], acc[ri][h*4+j], 0,0,0);
      }
    }
    __syncthreads();                             // LDS consumed; safe to restage
  }

  // ---- epilogue: exp -> Pt (swizzled LDS), row sums; then coalesced 16B stores ----
  char*  Pt   = lds;                             // 32 KB, [q 128][key 128] bf16
  float* lsum = (float*)(lds + 32768);
  #pragma unroll
  for (int ri=0;ri<2;++ri){
    const int q = w*32 + ri*16 + lr;             // local q row 0..127
    const uint32_t rswz = ((uint32_t)(q & 7)) << 4;
    float ps = 0.f;
    #pragma unroll
    for (int dj=0;dj<8;++dj){
      short4_t pv;
      #pragma unroll
      for (int r=0;r<4;++r){
        float pe = __expf(acc[ri][dj][r]);
        ps += pe;
        pv[r] = f2bf(pe);
      }
      *(short4_t*)(Pt + q*256 + (((uint32_t)(dj*32 + lg*8)) ^ rswz)) = pv;
    }
    ps += __shfl_xor(ps, 16, 64);                // reduce over the 4 lg groups
    ps += __shfl_xor(ps, 32, 64);
    if (lg == 0) lsum[q] = ps;
  }
  __syncthreads();
  #pragma unroll
  for (int i=0;i<8;++i){                         // 2048 chunks of 16B = full 32KB tile
    uint32_t c = (uint32_t)(i*256 + t);
    uint32_t row = c >> 4, c16 = c & 15;
    short8 v = *(short8*)(Pt + row*256 + ((c16*16) ^ (((uint32_t)(row & 7)) << 4)));
    *(short8*)(Pc + (size_t)(m0 + row)*chunk + blockIdx.x*128 + c16*8) = v;
  }
  if (t < 128){
    int jsl = (cbase >> 7) + blockIdx.x;         // 128-key slice index
    lpart[(size_t)jsl*ENC_B + m0 + t] = lsum[t];
  }
}

// ---------------- kernel 6: Z GEMM (R16 config), pure-write bf16 slices -------------
// zb[slice][512 d][8192 rows] bf16 = kvT[:, krange] @ Pc-slice (no RMW for nc=4).
// Tile 128 rows x 64 d, BK=64. grid dim3(64, 8, 2), 256 thr, 4 blocks/CU.
__global__ __launch_bounds__(256, 4) void z_gemm_kernel(const short* __restrict__ kvT,
                                                        const short* __restrict__ Pc,
                                                        short* __restrict__ zb,
                                                        int cbase, int chunk,
                                                        int sliceBase, int first){
  __shared__ __align__(16) short As[64*64];      // 8 KB  [d][k] swizzled
  __shared__ __align__(16) short Bs[128*64];     // 16 KB [row][k] swizzled
  const int t = threadIdx.x;
  const int lane = t & 63, w = t >> 6;
  const int lr = lane & 15, lg = lane >> 4;
  const int n0 = blockIdx.x * 128;               // q-rows
  const int m0 = blockIdx.y * 64;                // d
  const int s  = blockIdx.z;
  const int sl = sliceBase + s;
  const int klocal0 = s * (chunk >> 1);

  const short* Asrc[2];
  #pragma unroll
  for (int i=0;i<2;++i){
    int ca = i*256 + w*64 + lane;
    int row = ca >> 3;
    int kcs = (lane & 7) ^ (row & 7);
    Asrc[i] = kvT + (size_t)(m0 + row)*NFED + cbase + klocal0 + kcs*8;
  }
  const short* Bsrc[4];
  #pragma unroll
  for (int i=0;i<4;++i){
    int ca = i*256 + w*64 + lane;
    int row = ca >> 3;
    int kcs = (lane & 7) ^ (row & 7);
    Bsrc[i] = Pc + (size_t)(n0 + row)*chunk + klocal0 + kcs*8;
  }

  f32x4 acc[2][4];                               // [ri][dj]
  #pragma unroll
  for (int i=0;i<2;++i)
    #pragma unroll
    for (int j=0;j<4;++j) acc[i][j] = (f32x4){0.f,0.f,0.f,0.f};

  const int ksteps = chunk >> 7;                 // (chunk/2)/64
  for (int ks = 0; ks < ksteps; ++ks) {
    #pragma unroll
    for (int i=0;i<2;++i){
      gload16(Asrc[i], (char*)As + i*4096 + w*1024);
      Asrc[i] += 64;
    }
    #pragma unroll
    for (int i=0;i<4;++i){
      gload16(Bsrc[i], (char*)Bs + i*4096 + w*1024);
      Bsrc[i] += 64;
    }
    __syncthreads();                             // drains vmcnt: tiles ready

    #pragma unroll
    for (int kk=0;kk<2;++kk){
      const uint32_t kbyte = kk*64 + lg*16;
      short8 a[4], b[2];
      #pragma unroll
      for (int dj=0;dj<4;++dj){
        int row = dj*16 + lr;
        a[dj] = *(short8*)((char*)As + row*128 + (kbyte ^ ((uint32_t)(row & 7) << 4)));
      }
      #pragma unroll
      for (int ri=0;ri<2;++ri){
        int row = w*32 + ri*16 + lr;
        b[ri] = *(short8*)((char*)Bs + row*128 + (kbyte ^ ((uint32_t)(row & 7) << 4)));
      }
      #pragma unroll
      for (int ri=0;ri<2;++ri)
        #pragma unroll
        for (int dj=0;dj<4;++dj)
          acc[ri][dj] = __builtin_amdgcn_mfma_f32_16x16x32_bf16(a[dj], b[ri], acc[ri][dj], 0,0,0);
    }
    __syncthreads();                             // LDS consumed; safe to restage
  }

  #pragma unroll
  for (int ri=0;ri<2;++ri)
    #pragma unroll
    for (int dj=0;dj<4;++dj)
      #pragma unroll
      for (int r=0;r<4;++r) {
        int d    = m0 + dj*16 + lg*4 + r;
        int rowq = n0 + w*32 + ri*16 + lr;
        size_t idx = ((size_t)sl*LAT + d)*ENC_B + rowq;
        float v = acc[ri][dj][r];
        if (!first) v += bf2f(zb[idx]);
        zb[idx] = f2bf(v);
      }
}

// ---------------- kernel 7: linv[row] = 1 / sum_j lpart[j][row] ---------------------
__global__ __launch_bounds__(256) void lred_kernel(const float* __restrict__ lpart,
                                                   float* __restrict__ linv){
  const int row = blockIdx.x*256 + threadIdx.x;  // grid 32
  float sum = 0.f;
  for (int j = 0; j < NFED/128; ++j)
    sum += lpart[(size_t)j*ENC_B + row];
  linv[row] = 1.0f / sum;
}

// ---------------- kernel 8: out[row][d] = (sum_sl zb[sl][d][row]) * linv[row] -------
__global__ __launch_bounds__(256) void zcomb_kernel(const short* __restrict__ zb,
                                                    const float* __restrict__ linv,
                                                    float* __restrict__ out){
  __shared__ float tile[64][65];
  const int t = threadIdx.x;
  const int bx = blockIdx.x;                     // row-tile 0..127
  const int by = blockIdx.y;                     // d-tile 0..7
  #pragma unroll
  for (int i=0;i<4;++i){
    int idx = t + i*256;                         // 1024 quads = 64x64
    int dr = idx >> 4, rc = (idx & 15)*4;
    float s0=0.f, s1=0.f, s2=0.f, s3=0.f;
    #pragma unroll
    for (int sl=0; sl<8; ++sl){
      short4_t v = *(const short4_t*)(zb + ((size_t)sl*LAT + by*64 + dr)*ENC_B + bx*64 + rc);
      s0 += bf2f(v[0]); s1 += bf2f(v[1]); s2 += bf2f(v[2]); s3 += bf2f(v[3]);
    }
    tile[dr][rc+0]=s0; tile[dr][rc+1]=s1; tile[dr][rc+2]=s2; tile[dr][rc+3]=s3;
  }
  __syncthreads();
  #pragma unroll
  for (int i=0;i<4;++i){
    int idx = t + i*256;
    int rr = idx >> 4, dc = (idx & 15)*4;
    float li = linv[bx*64 + rr];
    float4 o;
    o.x = tile[dc+0][rr]*li; o.y = tile[dc+1][rr]*li;
    o.z = tile[dc+2][rr]*li; o.w = tile[dc+3][rr]*li;
    *(float4*)(out + (size_t)(bx*64+rr)*LAT + by*64 + dc) = o;
  }
}

extern "C" void kernel_launch(void* const* d_in, const int* in_sizes, int n_in,
                              void* d_out, int out_size, void* d_ws, size_t ws_size,
                              hipStream_t stream) {
  const float* enc = (const float*)d_in[0];   // 8192 x 512
  const float* X   = (const float*)d_in[1];   // 16384 x 1024
  const float* dd  = (const float*)d_in[2];   // 1024 x 512
  float* out = (float*)d_out;                  // 8192 x 512 f32

  // ws layout (bytes):
  //   kv    @ 0          16,777,216
  //   kvT   @ 16,777,216 16,777,216
  //   encb  @ 33,554,432  8,388,608
  //   lpart @ 41,943,040  4,194,304   (ddT overlays, dead before lpart use)
  //   linv  @ 46,137,344     32,768
  //   zb    @ 50,331,648 67,108,864   (Xb overlays first 32MB, dead before z writes)
  //   Pc    @117,440,512 chunk*16384
  short* kvb   = (short*)d_ws;
  short* kvT   = (short*)((char*)d_ws + 16777216);
  short* encb  = (short*)((char*)d_ws + 33554432);
  float* lpart = (float*)((char*)d_ws + 41943040);
  short* ddT   = (short*)((char*)d_ws + 41943040);   // prep only
  float* linv  = (float*)((char*)d_ws + 46137344);
  short* zb    = (short*)((char*)d_ws + 50331648);
  short* Xb    = (short*)((char*)d_ws + 50331648);   // prep only (dead before z)
  short* Pc    = (short*)((char*)d_ws + 117440512);

  int chunk;
  if      (ws_size >= (size_t)117440512 + (size_t)4096*ENC_B*2) chunk = 4096;
  else if (ws_size >= (size_t)117440512 + (size_t)2048*ENC_B*2) chunk = 2048;
  else                                                          chunk = 1024;

  ddT_kernel<<<LAT, 256, 0, stream>>>(dd, ddT);
  xb_kernel<<<NFED*INDIM/(256*8), 256, 0, stream>>>(X, Xb);
  kv_gemm_kernel<<<dim3(LAT/128, NFED/128), 256, 0, stream>>>(Xb, ddT, kvb, kvT);
  encb_kernel<<<ENC_B*LAT/(256*8), 256, 0, stream>>>(enc, encb);

  const int nc = NFED / chunk;
  for (int c = 0; c < nc; ++c) {
    s_gemm_kernel<<<dim3(chunk/128, ENC_B/128), 256, 0, stream>>>(
        encb, kvb, Pc, lpart, c*chunk, chunk);
    // slices: (c mod 4)*2 + splitK-half; pure write for c<4 (nc=4 => never RMW)
    z_gemm_kernel<<<dim3(ENC_B/128, LAT/64, 2), 256, 0, stream>>>(
        kvT, Pc, zb, c*chunk, chunk, (c & 3)*2, (c < 4) ? 1 : 0);
  }
  lred_kernel<<<ENC_B/256, 256, 0, stream>>>(lpart, linv);
  zcomb_kernel<<<dim3(ENC_B/64, LAT/64), 256, 0, stream>>>(zb, linv, out);
}